// Round 2
// baseline (170.245 us; speedup 1.0000x reference)
//
#include <hip/hip_runtime.h>
#include <hip/hip_bf16.h>

typedef _Float16 half8 __attribute__((ext_vector_type(8)));
typedef float f32x4 __attribute__((ext_vector_type(4)));

#define B_ 8
#define U_ 1024
#define N_ 2048
#define DIN 128
#define H_ 4
#define HD 32
#define S_ 3072
#define LOG2E 1.44269504f

// ---------------- phase 1: projections + e-vectors + transposed f16 V ----------------
// users blocks: q_user -> vtB (V for news-direction), e_q_un -> eRowA, e_k_nu -> eColB
// news  blocks: k_news -> vtA (V for user-direction), e_k_un -> eColA, e_q_nu -> eRowB
__global__ __launch_bounds__(256) void p1_kernel(
    const float* __restrict__ uf, const float* __restrict__ nf,
    const float* __restrict__ Wu, const float* __restrict__ Wn,
    const float* __restrict__ a_un, const float* __restrict__ a_nu,
    _Float16* __restrict__ vtA, _Float16* __restrict__ vtB,
    float4* __restrict__ eRowA, float4* __restrict__ eColA,
    float4* __restrict__ eRowB, float4* __restrict__ eColB)
{
  __shared__ float fs[64][132];    // feature tile, padded (conflict-free f4 reads)
  __shared__ float WsT[32][132];   // W transposed [k][d], padded
  __shared__ float qt[32][65];     // q tile transposed [k][u]
  __shared__ float aAs[32], aBs[32];

  const int bid = blockIdx.x;
  const int tid = threadIdx.x;

  int b, rt, R;
  const float *feat, *W;
  _Float16* vt;
  float4 *eA4, *eB4;
  int aAoff, aBoff;
  const float *avA, *avB;
  if (bid < 128) {                       // users
    b = bid >> 4; rt = bid & 15; R = U_;
    feat = uf; W = Wu; vt = vtB;
    eA4 = eRowA; eB4 = eColB;
    avA = a_un; aAoff = 0;  avB = a_nu; aBoff = HD;
  } else {                               // news
    int t2 = bid - 128;
    b = t2 >> 5; rt = t2 & 31; R = N_;
    feat = nf; W = Wn; vt = vtA;
    eA4 = eColA; eB4 = eRowB;
    avA = a_un; aAoff = HD; avB = a_nu; aBoff = 0;
  }
  const int r0 = rt * 64;
  const float4* feat4 = (const float4*)(feat + ((size_t)b * R + r0) * DIN);
  #pragma unroll
  for (int i = 0; i < 8; ++i) {
    int f4 = tid + 256 * i;              // 0..2047 float4s of the 64x128 tile
    int row = f4 >> 5, c4 = f4 & 31;
    *(float4*)&fs[row][c4 * 4] = feat4[row * 32 + c4];
  }

  const int kk = tid & 15, uu = tid >> 4;    // compute mapping: 2 k-cols x 4 u-rows
  const int u2 = tid & 63, part = tid >> 6;  // store/e mapping
  float eAv[H_], eBv[H_];

  #pragma unroll
  for (int h = 0; h < H_; ++h) {
    __syncthreads();
    {
      const float4* W4 = (const float4*)(W + (size_t)h * DIN * HD);
      #pragma unroll
      for (int i = 0; i < 4; ++i) {
        int f4 = tid + 256 * i;          // 0..1023
        int d = f4 >> 3, kc = f4 & 7;
        float4 v = W4[f4];
        WsT[kc * 4 + 0][d] = v.x;
        WsT[kc * 4 + 1][d] = v.y;
        WsT[kc * 4 + 2][d] = v.z;
        WsT[kc * 4 + 3][d] = v.w;
      }
      if (tid < 32) {
        aAs[tid] = avA[h * 64 + aAoff + tid];
        aBs[tid] = avB[h * 64 + aBoff + tid];
      }
    }
    __syncthreads();
    {
      float acc0[4] = {0.f, 0.f, 0.f, 0.f}, acc1[4] = {0.f, 0.f, 0.f, 0.f};
      #pragma unroll 8
      for (int d = 0; d < DIN; d += 4) {
        float4 w0 = *(const float4*)&WsT[kk][d];
        float4 w1 = *(const float4*)&WsT[kk + 16][d];
        #pragma unroll
        for (int i = 0; i < 4; ++i) {
          float4 fv = *(const float4*)&fs[uu + 16 * i][d];
          acc0[i] = fmaf(fv.x, w0.x, acc0[i]); acc0[i] = fmaf(fv.y, w0.y, acc0[i]);
          acc0[i] = fmaf(fv.z, w0.z, acc0[i]); acc0[i] = fmaf(fv.w, w0.w, acc0[i]);
          acc1[i] = fmaf(fv.x, w1.x, acc1[i]); acc1[i] = fmaf(fv.y, w1.y, acc1[i]);
          acc1[i] = fmaf(fv.z, w1.z, acc1[i]); acc1[i] = fmaf(fv.w, w1.w, acc1[i]);
        }
      }
      #pragma unroll
      for (int i = 0; i < 4; ++i) {
        qt[kk][uu + 16 * i] = acc0[i];
        qt[kk + 16][uu + 16 * i] = acc1[i];
      }
    }
    __syncthreads();
    {
      size_t vtbase = ((size_t)(b * H_ + h) * HD) * R + r0;
      #pragma unroll
      for (int jj = 0; jj < 8; ++jj) {
        int krow = part * 8 + jj;
        vt[vtbase + (size_t)krow * R + u2] = (_Float16)qt[krow][u2];
      }
      float a_ = 0.f, b2_ = 0.f;
      #pragma unroll
      for (int k2 = 0; k2 < HD; ++k2) {
        float qv = qt[k2][u2];
        a_  = fmaf(qv, aAs[k2], a_);
        b2_ = fmaf(qv, aBs[k2], b2_);
      }
      eAv[h] = a_  * LOG2E;   // pre-scale by log2(e): exp(x) == exp2(x*LOG2E)
      eBv[h] = b2_ * LOG2E;
    }
  }
  if (part == 0) {
    float4 v; v.x = eAv[0]; v.y = eAv[1]; v.z = eAv[2]; v.w = eAv[3];
    eA4[(size_t)b * R + r0 + u2] = v;
  } else if (part == 1) {
    float4 v; v.x = eBv[0]; v.y = eBv[1]; v.z = eBv[2]; v.w = eBv[3];
    eB4[(size_t)b * R + r0 + u2] = v;
  }
}

// ---------------- phase 2: fused masked-softmax-weighted GEMM (both directions) ----------------
// Each wave: 16 rows, all 4 heads. A-frag = w (computed in regs), B-frag = VT 16B load.
// 3 MFMAs per head per 32-col tile: 2 numerator + 1 ones-B denominator.
// num layout: [b][h][row][hd]  (matches the reference's raw (B,H,R,HD)->(B,R,128) reshape)
// den layout: [b][h][row]
__global__ __launch_bounds__(256) void p2_kernel(
    const int* __restrict__ adj,
    const _Float16* __restrict__ vtA, const _Float16* __restrict__ vtB,
    const float4* __restrict__ eRowA, const float4* __restrict__ eColA,
    const float4* __restrict__ eRowB, const float4* __restrict__ eColB,
    float* __restrict__ numA, float* __restrict__ denA,
    float* __restrict__ numB, float* __restrict__ denB)
{
  const int bid = blockIdx.x;
  const int tid = threadIdx.x;
  const int wave = tid >> 6, l = tid & 63;

  int b, rt, R, C, r_off, c_off, c0;
  const _Float16* vt;
  const float4 *eRow, *eCol;
  float *num, *den;
  if (bid < 256) {                      // direction A (rows=users), 2 col-chunks of 1024
    b = bid & 7; rt = (bid >> 3) & 15; int g = bid >> 7;
    R = U_; C = N_; r_off = 0; c_off = U_;
    vt = vtA; eRow = eRowA; eCol = eColA;
    num = numA + (size_t)g * ((size_t)B_ * U_ * 128);
    den = denA + (size_t)g * (B_ * U_ * H_);
    c0 = g * 1024;
  } else {                              // direction B (rows=news), full 1024 cols
    int t2 = bid - 256;
    b = t2 & 7; rt = (t2 >> 3) & 31;
    R = N_; C = U_; r_off = U_; c_off = 0;
    vt = vtB; eRow = eRowB; eCol = eColB;
    num = numB; den = denB;
    c0 = 0;
  }
  const int r = rt * 64 + wave * 16 + (l & 15);
  const int cg = (l >> 4) << 3;                     // lane-group K offset: 0,8,16,24
  const float4 eq4 = eRow[(size_t)b * R + r];
  const int* adjRow = adj + (size_t)b * S_ * S_ + (size_t)(r_off + r) * S_ + c_off;
  const float4* ecol = eCol + (size_t)b * C;
  const _Float16* vtb = vt + ((size_t)b * H_ * HD) * C;

  f32x4 zero4 = {0.f, 0.f, 0.f, 0.f};
  f32x4 acc[H_][2], accd[H_];
  #pragma unroll
  for (int h = 0; h < H_; ++h) { acc[h][0] = zero4; acc[h][1] = zero4; accd[h] = zero4; }
  half8 ones = {(_Float16)1.f, (_Float16)1.f, (_Float16)1.f, (_Float16)1.f,
                (_Float16)1.f, (_Float16)1.f, (_Float16)1.f, (_Float16)1.f};

  const float eqh_[4] = {eq4.x, eq4.y, eq4.z, eq4.w};

  for (int t = 0; t < 32; ++t) {
    const int cb = c0 + t * 32 + cg;
    int4 A0 = *(const int4*)(adjRow + cb);
    int4 A1 = *(const int4*)(adjRow + cb + 4);
    int av[8] = {A0.x, A0.y, A0.z, A0.w, A1.x, A1.y, A1.z, A1.w};
    float ecv[8][4];
    #pragma unroll
    for (int j = 0; j < 8; ++j) {
      float4 e4 = ecol[cb + j];
      ecv[j][0] = e4.x; ecv[j][1] = e4.y; ecv[j][2] = e4.z; ecv[j][3] = e4.w;
    }
    #pragma unroll
    for (int h = 0; h < H_; ++h) {
      half8 w;
      #pragma unroll
      for (int j = 0; j < 8; ++j) {
        float s  = eqh_[h] + ecv[j][h];           // already log2e-scaled
        float ls = s > 0.f ? s : 0.2f * s;        // leaky commutes with positive scale
        float wv = av[j] ? exp2f(ls) : 0.f;       // masked -> exact 0 weight
        w[j] = (_Float16)wv;
      }
      const half8 b0 = *(const half8*)(vtb + ((size_t)h * HD + (l & 15)) * C + cb);
      const half8 b1 = *(const half8*)(vtb + ((size_t)h * HD + (l & 15) + 16) * C + cb);
      acc[h][0] = __builtin_amdgcn_mfma_f32_16x16x32_f16(w, b0, acc[h][0], 0, 0, 0);
      acc[h][1] = __builtin_amdgcn_mfma_f32_16x16x32_f16(w, b1, acc[h][1], 0, 0, 0);
      accd[h]   = __builtin_amdgcn_mfma_f32_16x16x32_f16(w, ones, accd[h], 0, 0, 0);
    }
  }
  const int colk = l & 15;
  const int rowbase = rt * 64 + wave * 16 + ((l >> 4) << 2);
  #pragma unroll
  for (int h = 0; h < H_; ++h) {
    #pragma unroll
    for (int q = 0; q < 4; ++q) {
      int row = rowbase + q;                       // C layout: col=l&15, row=(l>>4)*4+q
      size_t o = ((size_t)(b * H_ + h) * R + row) * 32 + colk;
      num[o] = acc[h][0][q];
      num[o + 16] = acc[h][1][q];
      if (colk == 0) den[(size_t)(b * H_ + h) * R + row] = accd[h][q];
    }
  }
}

// ---------------- phase 3: combine partials, divide, bias, relu ----------------
// out flat idx = b*(H*R*HD) + h*(R*HD) + row*HD + k  == num idx exactly.
// bias index = idx & 127 (the reference adds b_user over the last axis of the raw reshape).
__global__ __launch_bounds__(256) void p3_kernel(
    const float* __restrict__ numA, const float* __restrict__ denA,
    const float* __restrict__ numB, const float* __restrict__ denB,
    const float* __restrict__ bu, const float* __restrict__ bn,
    float* __restrict__ out)
{
  int idx = blockIdx.x * 256 + threadIdx.x;
  const int nU = B_ * U_ * 128;                    // 1048576
  if (idx < nU) {
    float n = numA[idx] + numA[idx + nU];
    float d = denA[idx >> 5] + denA[(idx >> 5) + B_ * U_ * H_];
    float v = n / d + bu[idx & 127];
    out[idx] = v > 0.f ? v : 0.f;
  } else {
    int i2 = idx - nU;
    float v = numB[i2] / denB[i2 >> 5] + bn[i2 & 127];
    out[idx] = v > 0.f ? v : 0.f;
  }
}

extern "C" void kernel_launch(void* const* d_in, const int* in_sizes, int n_in,
                              void* d_out, int out_size, void* d_ws, size_t ws_size,
                              hipStream_t stream) {
  const float* uf  = (const float*)d_in[0];
  const float* nf  = (const float*)d_in[1];
  const int*   adj = (const int*)d_in[2];
  const float* Wu  = (const float*)d_in[3];
  const float* Wn  = (const float*)d_in[4];
  const float* aun = (const float*)d_in[5];
  const float* anu = (const float*)d_in[6];
  const float* bu  = (const float*)d_in[7];
  const float* bn  = (const float*)d_in[8];

  char* ws = (char*)d_ws;
  size_t off = 0;
  _Float16* vtA = (_Float16*)(ws + off); off += (size_t)B_ * H_ * HD * N_ * 2;  // 4 MB
  _Float16* vtB = (_Float16*)(ws + off); off += (size_t)B_ * H_ * HD * U_ * 2;  // 2 MB
  float4* eRowA = (float4*)(ws + off); off += (size_t)B_ * U_ * 16;
  float4* eColA = (float4*)(ws + off); off += (size_t)B_ * N_ * 16;
  float4* eRowB = (float4*)(ws + off); off += (size_t)B_ * N_ * 16;
  float4* eColB = (float4*)(ws + off); off += (size_t)B_ * U_ * 16;
  float* numA = (float*)(ws + off); off += (size_t)2 * B_ * U_ * 128 * 4;       // 8 MB
  float* denA = (float*)(ws + off); off += (size_t)2 * B_ * U_ * H_ * 4;
  float* numB = (float*)(ws + off); off += (size_t)B_ * N_ * 128 * 4;           // 8 MB
  float* denB = (float*)(ws + off); off += (size_t)B_ * N_ * H_ * 4;
  (void)off; (void)ws_size; (void)in_sizes; (void)n_in; (void)out_size;        // ~24.4 MB total

  p1_kernel<<<384, 256, 0, stream>>>(uf, nf, Wu, Wn, aun, anu,
                                     vtA, vtB, eRowA, eColA, eRowB, eColB);
  p2_kernel<<<512, 256, 0, stream>>>(adj, vtA, vtB, eRowA, eColA, eRowB, eColB,
                                     numA, denA, numB, denB);
  p3_kernel<<<12288, 256, 0, stream>>>(numA, denA, numB, denB, bu, bn, (float*)d_out);
}